// Round 14
// baseline (306.038 us; speedup 1.0000x reference)
//
#include <hip/hip_runtime.h>
#include <hip/hip_bf16.h>

// TriangleMultiplicativeUpdate (outgoing), N=1 S=512 Z=E=128. f32 in/out.
// R14 vs R13 (k2 latency-bound, nothing >40% busy):
//  (1) k2: depth-1 register prefetch of next-t B-frags (load latency hides
//      under the sigmoid/pack epilogue); __launch_bounds__(256,3).
//  (2) all kernels: f2bf -> native __float2bfloat16 (was 4 integer ops).
// k_pack/k3/k3b/k4 otherwise identical to R13 (passing, 302us, absmax 0.03125).

typedef unsigned short u16;
typedef unsigned int u32;
typedef __attribute__((ext_vector_type(8))) short bf16x8;
typedef __attribute__((ext_vector_type(4))) float f32x4;

#define SD 512
#define NROWS 262144

__device__ __forceinline__ float bf2f(u32 u){ u32 x = u << 16; float f; __builtin_memcpy(&f,&x,4); return f; }
__device__ __forceinline__ u16 f2bf(float f){
  __hip_bfloat16 h = __float2bfloat16(f);
  u16 r; __builtin_memcpy(&r, &h, 2); return r;
}
__device__ __forceinline__ float sigm(float x){ return 1.0f/(1.0f+__expf(-x)); }

__global__ void k_marker(float* out, float v){
  if (threadIdx.x == 0 && blockIdx.x == 0) out[0] = v;
}

// ---- pack weights (f32) into bf16 16x16x32 B-fragment order
__global__ void k_pack(const float* w0, const float* w1, const float* w2, const float* w3,
                       const float* w4, const float* w5, u16* packed)
{
  const int w = blockIdx.x;
  const float* src = (w==0)?w0:(w==1)?w1:(w==2)?w2:(w==3)?w3:(w==4)?w4:w5;
  u16* dst = packed + w*16384;
  for (int idx = threadIdx.x; idx < 16384; idx += 256){
    const int t = idx >> 11, kk = (idx >> 9) & 3, l = (idx >> 3) & 63, j = idx & 7;
    const int k = kk*32 + (l>>4)*8 + j, n = t*16 + (l&15);
    dst[idx] = f2bf(src[k*128 + n]);
  }
}

// ---- K2: LN1 + 4 projections (MFMA), sigmoid-mul, transpose-write [e][g].
//      R14: depth-1 B-frag prefetch across t; native bf16 cvt.
__global__ __launch_bounds__(256, 3) void k2(
    const float* __restrict__ pair, const float* __restrict__ ln1w, const float* __restrict__ ln1b,
    const u16* __restrict__ packed, u16* __restrict__ Lb, u16* __restrict__ Rb)
{
  __shared__ alignas(16) u16 repL[128*64];
  __shared__ alignas(16) u16 repR[128*64];
  const int tid = threadIdx.x, wave = tid >> 6, lane = tid & 63;
  const int row0 = blockIdx.x * 64;
  const int ar = lane & 15, q8 = lane >> 4;
  const size_t grow = row0 + wave*16 + ar;

  float v[32];
  float sum = 0.f;
  #pragma unroll
  for (int kk = 0; kk < 4; ++kk){
    const float4 r0 = *(const float4*)(pair + grow*128 + kk*32 + q8*8);
    const float4 r1 = *(const float4*)(pair + grow*128 + kk*32 + q8*8 + 4);
    v[kk*8+0]=r0.x; v[kk*8+1]=r0.y; v[kk*8+2]=r0.z; v[kk*8+3]=r0.w;
    v[kk*8+4]=r1.x; v[kk*8+5]=r1.y; v[kk*8+6]=r1.z; v[kk*8+7]=r1.w;
    sum += r0.x+r0.y+r0.z+r0.w + r1.x+r1.y+r1.z+r1.w;
  }
  sum += __shfl_xor(sum, 16); sum += __shfl_xor(sum, 32);
  const float m = sum * (1.f/128.f);
  float sq = 0.f;
  #pragma unroll
  for (int i = 0; i < 32; ++i){ const float d = v[i]-m; sq += d*d; }
  sq += __shfl_xor(sq, 16); sq += __shfl_xor(sq, 32);
  const float rs = rsqrtf(sq*(1.f/128.f) + 1e-5f);

  bf16x8 xf[4];
  #pragma unroll
  for (int kk = 0; kk < 4; ++kk){
    bf16x8 f;
    #pragma unroll
    for (int j = 0; j < 8; ++j){
      const int k = kk*32 + q8*8 + j;
      f[j] = (short)f2bf((v[kk*8+j]-m)*rs*ln1w[k] + ln1b[k]);
    }
    xf[kk] = f;
  }

  bf16x8 cur0[4], cur1[4], cur2[4], cur3[4];
  bf16x8 nx0[4], nx1[4], nx2[4], nx3[4];
  auto loadT = [&](int t, bf16x8* c0, bf16x8* c1, bf16x8* c2, bf16x8* c3){
    #pragma unroll
    for (int kk = 0; kk < 4; ++kk){
      const size_t bo = (size_t)t*2048 + kk*512 + lane*8;
      c0[kk] = *(const bf16x8*)(packed + 0*16384 + bo);
      c1[kk] = *(const bf16x8*)(packed + 1*16384 + bo);
      c2[kk] = *(const bf16x8*)(packed + 2*16384 + bo);
      c3[kk] = *(const bf16x8*)(packed + 3*16384 + bo);
    }
  };

  const f32x4 vz = {0.f,0.f,0.f,0.f};
  loadT(0, cur0, cur1, cur2, cur3);
  #pragma unroll 1
  for (int t = 0; t < 8; ++t){
    f32x4 a0 = vz, a1 = vz, a2 = vz, a3 = vz;
    #pragma unroll
    for (int kk = 0; kk < 4; ++kk){
      a0 = __builtin_amdgcn_mfma_f32_16x16x32_bf16(xf[kk], cur0[kk], a0, 0,0,0);
      a1 = __builtin_amdgcn_mfma_f32_16x16x32_bf16(xf[kk], cur1[kk], a1, 0,0,0);
      a2 = __builtin_amdgcn_mfma_f32_16x16x32_bf16(xf[kk], cur2[kk], a2, 0,0,0);
      a3 = __builtin_amdgcn_mfma_f32_16x16x32_bf16(xf[kk], cur3[kk], a3, 0,0,0);
    }
    if (t < 7) loadT(t+1, nx0, nx1, nx2, nx3);   // prefetch hides under epilogue

    const int e = t*16 + ar;
    const int swz = (e & 7) << 3;
    const int rbase = (wave*16 + q8*4) ^ swz;
    const u32 lw0 = (u32)f2bf(sigm(a0[0])*a1[0]) | ((u32)f2bf(sigm(a0[1])*a1[1]) << 16);
    const u32 lw1 = (u32)f2bf(sigm(a0[2])*a1[2]) | ((u32)f2bf(sigm(a0[3])*a1[3]) << 16);
    const u32 rw0 = (u32)f2bf(sigm(a2[0])*a3[0]) | ((u32)f2bf(sigm(a2[1])*a3[1]) << 16);
    const u32 rw1 = (u32)f2bf(sigm(a2[2])*a3[2]) | ((u32)f2bf(sigm(a2[3])*a3[3]) << 16);
    *(uint2*)(repL + e*64 + rbase) = make_uint2(lw0, lw1);
    *(uint2*)(repR + e*64 + rbase) = make_uint2(rw0, rw1);

    #pragma unroll
    for (int kk = 0; kk < 4; ++kk){
      cur0[kk] = nx0[kk]; cur1[kk] = nx1[kk];
      cur2[kk] = nx2[kk]; cur3[kk] = nx3[kk];
    }
  }
  __syncthreads();

  #pragma unroll
  for (int it = 0; it < 4; ++it){
    const int c = it*256 + tid;
    const int e = c >> 3, ch = c & 7;
    const int chp = (ch ^ (e & 7)) * 8;
    *(uint4*)(Lb + (size_t)e*NROWS + row0 + ch*8) = *(const uint4*)(repL + e*64 + chp);
    *(uint4*)(Rb + (size_t)e*NROWS + row0 + ch*8) = *(const uint4*)(repR + e*64 + chp);
  }
}

// ---- K3: block (e,ti): A panel resident in LDS; stream B tiles; blocked C. (unchanged)
__global__ __launch_bounds__(512, 2) void k3(
    const u16* __restrict__ Lb, const u16* __restrict__ Rb, u16* __restrict__ pT)
{
  __shared__ alignas(16) u16 Apan[128*512];
  __shared__ alignas(16) u16 Bb[128*64];
  const int tid = threadIdx.x, wave = tid >> 6, lane = tid & 63;
  const int e = blockIdx.x & 127, ti = blockIdx.x >> 7;
  const u16* aSrc = Lb + (size_t)e*NROWS + (size_t)ti*128*SD;
  const u16* bSrc = Rb + (size_t)e*NROWS;
  const int wm = wave >> 2, wn = wave & 3;
  const int fr = lane & 15, fq = lane >> 4;

  {
    const int lane32 = tid & 31, grp = tid >> 5;
    #pragma unroll
    for (int c = 0; c < 16; ++c){
      const int row = grp*8 + (c >> 1);
      const int off = lane32*16 + (c & 1)*512;
      const uint4 v = *(const uint4*)((const char*)(aSrc + (size_t)row*SD) + off);
      *(uint4*)((char*)Apan + row*1024 + (off ^ ((row & 7) << 4))) = v;
    }
  }

  const int brow = tid >> 2, bseg = tid & 3;
  const int bswz = (brow & 7) << 4;
  uint4 bA0, bA1, bB0, bB1;
  auto loadB = [&](int t, uint4& r0, uint4& r1){
    const int tj = t >> 3, rs = t & 7;
    const char* src = (const char*)(bSrc + (size_t)(tj*128 + brow)*SD + rs*64);
    r0 = *(const uint4*)(src + bseg*32);
    r1 = *(const uint4*)(src + bseg*32 + 16);
  };
  auto dsWriteB = [&](const uint4& r0, const uint4& r1){
    char* dst = (char*)Bb + brow*128;
    *(uint4*)(dst + ((bseg*32)      ^ bswz)) = r0;
    *(uint4*)(dst + ((bseg*32 + 16) ^ bswz)) = r1;
  };

  const f32x4 vz = {0.f,0.f,0.f,0.f};
  f32x4 acc[4][2];
  #pragma unroll
  for (int a = 0; a < 4; ++a){ acc[a][0] = vz; acc[a][1] = vz; }

  auto compute = [&](int t){
    const int rs = t & 7;
    #pragma unroll
    for (int kk = 0; kk < 2; ++kk){
      bf16x8 af[4], bf[2];
      #pragma unroll
      for (int mt = 0; mt < 4; ++mt){
        const int row = wm*64 + mt*16 + fr;
        af[mt] = *(const bf16x8*)((const char*)Apan + row*1024 + rs*128 + ((kk*64 + fq*16) ^ ((row&7)<<4)));
      }
      #pragma unroll
      for (int nt = 0; nt < 2; ++nt){
        const int row = wn*32 + nt*16 + fr;
        bf[nt] = *(const bf16x8*)((const char*)Bb + row*128 + ((kk*64 + fq*16) ^ ((row&7)<<4)));
      }
      #pragma unroll
      for (int mt = 0; mt < 4; ++mt)
        #pragma unroll
        for (int nt = 0; nt < 2; ++nt)
          acc[mt][nt] = __builtin_amdgcn_mfma_f32_16x16x32_bf16(af[mt], bf[nt], acc[mt][nt], 0,0,0);
    }
    if ((t & 7) == 7){
      const int tj = t >> 3;
      u16* base = pT + (size_t)((e*4 + ti)*4 + tj)*16384;
      #pragma unroll
      for (int mt = 0; mt < 4; ++mt){
        #pragma unroll
        for (int nt = 0; nt < 2; ++nt){
          const int row = wm*64 + mt*16 + fq*4;
          const int col = wn*32 + nt*16 + fr;
          #pragma unroll
          for (int i = 0; i < 4; ++i)
            base[(row + i)*128 + col] = f2bf(acc[mt][nt][i]);
          acc[mt][nt] = vz;
        }
      }
    }
  };

  loadB(0, bA0, bA1);
  loadB(1, bB0, bB1);
  #pragma unroll 1
  for (int t = 0; t < 32; t += 2){
    __syncthreads();
    dsWriteB(bA0, bA1);
    if (t + 2 < 32) loadB(t + 2, bA0, bA1);
    __syncthreads();
    compute(t);
    __syncthreads();
    dsWriteB(bB0, bB1);
    if (t + 3 < 32) loadB(t + 3, bB0, bB1);
    __syncthreads();
    compute(t + 1);
  }
}

// ---- K3b: blocked pT -> transpose -> LN2 over e -> pn[k*512+s][e]. (unchanged)
__global__ __launch_bounds__(256) void k3b(
    const u16* __restrict__ pT, const float* __restrict__ ln2w, const float* __restrict__ ln2b,
    u16* __restrict__ pn)
{
  __shared__ alignas(16) u16 tile[64*130];
  const int tid = threadIdx.x;
  const int f0 = blockIdx.x * 64;
  const int s = f0 >> 9, k0 = f0 & 511;
  const int ti = s >> 7, tj = k0 >> 7;
  const int rloc = s & 127, kbase = k0 & 127;
  #pragma unroll
  for (int it = 0; it < 4; ++it){
    const int c = it*256 + tid;
    const int ee = c >> 3, ch = c & 7;
    const uint4 vv = *(const uint4*)(pT + (size_t)((ee*4 + ti)*4 + tj)*16384 + rloc*128 + kbase + ch*8);
    const u32 wd[4] = {vv.x, vv.y, vv.z, vv.w};
    #pragma unroll
    for (int q = 0; q < 4; ++q){
      tile[(ch*8 + q*2    )*130 + ee] = (u16)(wd[q] & 0xffffu);
      tile[(ch*8 + q*2 + 1)*130 + ee] = (u16)(wd[q] >> 16);
    }
  }
  __syncthreads();
  #pragma unroll
  for (int it = 0; it < 4; ++it){
    const int c = it*256 + tid;
    const int fl = c >> 4, ch = c & 15;
    const u16* trow = tile + fl*130 + ch*8;
    float x[8];
    #pragma unroll
    for (int q = 0; q < 8; ++q){ u32 u = (u32)trow[q] << 16; __builtin_memcpy(&x[q], &u, 4); }
    float sum = 0.f;
    #pragma unroll
    for (int q = 0; q < 8; ++q) sum += x[q];
    sum += __shfl_xor(sum, 1); sum += __shfl_xor(sum, 2);
    sum += __shfl_xor(sum, 4); sum += __shfl_xor(sum, 8);
    const float m = sum*(1.f/128.f);
    float sq = 0.f;
    #pragma unroll
    for (int q = 0; q < 8; ++q){ const float d = x[q]-m; sq += d*d; }
    sq += __shfl_xor(sq, 1); sq += __shfl_xor(sq, 2);
    sq += __shfl_xor(sq, 4); sq += __shfl_xor(sq, 8);
    const float rs = rsqrtf(sq*(1.f/128.f) + 1e-5f);
    u32 o[4];
    #pragma unroll
    for (int q = 0; q < 4; ++q){
      const float a = (x[q*2]   - m)*rs*ln2w[ch*8+q*2]   + ln2b[ch*8+q*2];
      const float b = (x[q*2+1] - m)*rs*ln2w[ch*8+q*2+1] + ln2b[ch*8+q*2+1];
      o[q] = (u32)f2bf(a) | ((u32)f2bf(b) << 16);
    }
    const size_t orow = (size_t)(k0 + fl)*SD + s;
    *(uint4*)(pn + orow*128 + ch*8) = make_uint4(o[0],o[1],o[2],o[3]);
  }
}

// ---- K4: out = pair + (pn@out_w)*sigm(LN1(pair)@gate). (unchanged)
__global__ __launch_bounds__(256) void k4(
    const float* __restrict__ pair, const float* __restrict__ ln1w, const float* __restrict__ ln1b,
    const u16* __restrict__ pn, const u16* __restrict__ packed, float* __restrict__ out)
{
  __shared__ alignas(16) float qf[4][16*128];
  const int tid = threadIdx.x, wave = tid >> 6, lane = tid & 63;
  const int row0 = blockIdx.x * 64;
  const int ar = lane & 15, q8 = lane >> 4;
  const size_t fG = row0 + wave*16 + ar;

  float v[32];
  float sum = 0.f;
  #pragma unroll
  for (int kk = 0; kk < 4; ++kk){
    const float4 r0 = *(const float4*)(pair + fG*128 + kk*32 + q8*8);
    const float4 r1 = *(const float4*)(pair + fG*128 + kk*32 + q8*8 + 4);
    v[kk*8+0]=r0.x; v[kk*8+1]=r0.y; v[kk*8+2]=r0.z; v[kk*8+3]=r0.w;
    v[kk*8+4]=r1.x; v[kk*8+5]=r1.y; v[kk*8+6]=r1.z; v[kk*8+7]=r1.w;
    sum += r0.x+r0.y+r0.z+r0.w + r1.x+r1.y+r1.z+r1.w;
  }
  sum += __shfl_xor(sum, 16); sum += __shfl_xor(sum, 32);
  const float m = sum * (1.f/128.f);
  float sq = 0.f;
  #pragma unroll
  for (int i = 0; i < 32; ++i){ const float d = v[i]-m; sq += d*d; }
  sq += __shfl_xor(sq, 16); sq += __shfl_xor(sq, 32);
  const float rs = rsqrtf(sq*(1.f/128.f) + 1e-5f);

  bf16x8 xf[4], pf[4];
  #pragma unroll
  for (int kk = 0; kk < 4; ++kk){
    bf16x8 f;
    #pragma unroll
    for (int j = 0; j < 8; ++j){
      const int k = kk*32 + q8*8 + j;
      f[j] = (short)f2bf((v[kk*8+j]-m)*rs*ln1w[k] + ln1b[k]);
    }
    xf[kk] = f;
    pf[kk] = *(const bf16x8*)(pn + fG*128 + kk*32 + q8*8);
  }

  const f32x4 vz = {0.f,0.f,0.f,0.f};
  #pragma unroll 1
  for (int t = 0; t < 8; ++t){
    f32x4 aQ = vz, aG = vz;
    #pragma unroll
    for (int kk = 0; kk < 4; ++kk){
      const size_t bo = (size_t)t*2048 + kk*512 + lane*8;
      aQ = __builtin_amdgcn_mfma_f32_16x16x32_bf16(pf[kk], *(const bf16x8*)(packed + 4*16384 + bo), aQ, 0,0,0);
      aG = __builtin_amdgcn_mfma_f32_16x16x32_bf16(xf[kk], *(const bf16x8*)(packed + 5*16384 + bo), aG, 0,0,0);
    }
    #pragma unroll
    for (int i = 0; i < 4; ++i)
      qf[wave][(q8*4 + i)*128 + t*16 + ar] = aQ[i]*sigm(aG[i]);
  }
  __syncthreads();

  #pragma unroll
  for (int it = 0; it < 8; ++it){
    const int c = it*256 + tid;
    const int rowL = c >> 5, seg = c & 31;
    const size_t row = row0 + rowL;
    const float4 pv = *(const float4*)(pair + row*128 + seg*4);
    const float* qp = &qf[rowL >> 4][(rowL & 15)*128 + seg*4];
    float4 ov;
    ov.x = pv.x + qp[0]; ov.y = pv.y + qp[1];
    ov.z = pv.z + qp[2]; ov.w = pv.w + qp[3];
    *(float4*)(out + row*128 + seg*4) = ov;
  }
}

extern "C" void kernel_launch(void* const* d_in, const int* in_sizes, int n_in,
                              void* d_out, int out_size, void* d_ws, size_t ws_size,
                              hipStream_t stream)
{
  (void)in_sizes; (void)n_in; (void)out_size;
  const float* pair = (const float*)d_in[0];
  const float* ln1w = (const float*)d_in[1];
  const float* ln1b = (const float*)d_in[2];
  const float* w_l1 = (const float*)d_in[3];
  const float* w_l2 = (const float*)d_in[4];
  const float* w_r1 = (const float*)d_in[5];
  const float* w_r2 = (const float*)d_in[6];
  const float* ln2w = (const float*)d_in[7];
  const float* ln2b = (const float*)d_in[8];
  const float* w_ow = (const float*)d_in[9];
  const float* w_gt = (const float*)d_in[10];
  float* outp = (float*)d_out;
  char* ws = (char*)d_ws;

  const size_t NEED = (size_t)67108864*3 + 196608;   // 192.2 MiB
  if (ws_size < NEED){
    k_marker<<<dim3(1), dim3(1), 0, stream>>>(outp, 1e6f*(float)(ws_size >> 20));
    return;
  }

  u16* Lb     = (u16*)ws;                           // 64 MiB; pn overlays after k3
  u16* Rb     = (u16*)(ws + (size_t)67108864);      // 64 MiB
  u16* pT     = (u16*)(ws + (size_t)134217728);     // 64 MiB (blocked tiles)
  u16* packed = (u16*)(ws + (size_t)201326592);     // 192 KiB
  u16* pn     = Lb;                                 // overlay: Lb dead after k3

  k_pack<<<dim3(6),    dim3(256), 0, stream>>>(w_l1, w_l2, w_r1, w_r2, w_ow, w_gt, packed);
  k2    <<<dim3(4096), dim3(256), 0, stream>>>(pair, ln1w, ln1b, packed, Lb, Rb);
  k3    <<<dim3(512),  dim3(512), 0, stream>>>(Lb, Rb, pT);
  k3b   <<<dim3(4096), dim3(256), 0, stream>>>(pT, ln2w, ln2b, pn);
  k4    <<<dim3(4096), dim3(256), 0, stream>>>(pair, ln1w, ln1b, pn, packed, outp);
}